// Round 1
// baseline (967.154 us; speedup 1.0000x reference)
//
#include <hip/hip_runtime.h>
#include <cstddef>

#define NPTS 500000
#define DF 64
#define NC 10000
#define BN_EPS 1e-5f
#define NBLK 2048
#define NWAVE (NBLK * 4)
#define PPW ((NPTS + NWAVE - 1) / NWAVE)   // 62 points per wave

// ---- order-preserving float<->uint encoding (for atomic max on floats) ----
__device__ __forceinline__ unsigned f2o(float f) {
  unsigned u = __float_as_uint(f);
  return (u & 0x80000000u) ? ~u : (u | 0x80000000u);
}
__device__ __forceinline__ float o2f(unsigned u) {
  return __uint_as_float((u & 0x80000000u) ? (u ^ 0x80000000u) : ~u);
}

// ws layout (float/uint units):
// 0        : q_u     [NC*DF]   sortable-uint segment max of Q projections
// 640000   : mmax_u  [NC]      sortable-uint segment max of M
// 650000   : denom   [NC]      segment sum of exp
// 660000   : sums    [2*DF]    [sum h | sum h^2]
// 660128   : scale   [DF]
// 660192   : shift   [DF]
// 660256   : Mv      [NPTS]
// total 1,160,256 floats = 4.64 MB

// MODE 0: Q proj -> atomicMax q_u
// MODE 1: K proj -> M = dot(q[c],k), store Mv, atomicMax mmax_u
// MODE 2: V proj -> h = attn*v, accumulate BN stats (no store)
// MODE 3: V proj -> h, normalize + relu, write out
template <int MODE>
__global__ void proj_kernel(
    const float* __restrict__ x, const int* __restrict__ cluster,
    const float* __restrict__ W, const float* __restrict__ bias,
    unsigned* __restrict__ q_u, unsigned* __restrict__ mmax_u,
    float* __restrict__ denom, float* __restrict__ Mv,
    float* __restrict__ sums, const float* __restrict__ scale,
    const float* __restrict__ shift, float* __restrict__ out) {
  const int lane = threadIdx.x & 63;
  const int wid = (blockIdx.x * blockDim.x + threadIdx.x) >> 6;

  // W row for this lane's output feature, held in registers (64 VGPRs)
  float4 w[16];
#pragma unroll
  for (int j4 = 0; j4 < 16; ++j4)
    w[j4] = *(const float4*)(W + lane * DF + j4 * 4);
  const float bd = bias[lane];

  float sc = 0.f, sh = 0.f;
  if (MODE == 3) { sc = scale[lane]; sh = shift[lane]; }

  float s1 = 0.f, s2 = 0.f;

  const int p0 = wid * PPW;
  const int p1 = (p0 + PPW < NPTS) ? (p0 + PPW) : NPTS;
  for (int p = p0; p < p1; ++p) {
    // p is wave-uniform; readfirstlane lets the compiler emit scalar loads
    const int pu = __builtin_amdgcn_readfirstlane(p);
    const float* xp = x + (size_t)pu * DF;
    float acc = bd;
#pragma unroll
    for (int j4 = 0; j4 < 16; ++j4) {
      const float4 xv = *(const float4*)(xp + j4 * 4);
      acc = fmaf(w[j4].x, xv.x, acc);
      acc = fmaf(w[j4].y, xv.y, acc);
      acc = fmaf(w[j4].z, xv.z, acc);
      acc = fmaf(w[j4].w, xv.w, acc);
    }
    const int c = __builtin_amdgcn_readfirstlane(cluster[pu]);
    if (MODE == 0) {
      atomicMax(q_u + c * DF + lane, f2o(acc));
    } else if (MODE == 1) {
      float prod = o2f(q_u[c * DF + lane]) * acc;
#pragma unroll
      for (int m = 32; m >= 1; m >>= 1) prod += __shfl_xor(prod, m, 64);
      if (lane == 0) {
        Mv[pu] = prod;
        atomicMax(mmax_u + c, f2o(prod));
      }
    } else {
      const float attn = __expf(Mv[pu] - o2f(mmax_u[c])) / denom[c];
      const float h = attn * acc;
      if (MODE == 2) {
        s1 += h;
        s2 += h * h;
      } else {
        out[(size_t)pu * DF + lane] = fmaxf(fmaf(h, sc, sh), 0.f);
      }
    }
  }

  if constexpr (MODE == 2) {
    __shared__ float r1[4][DF];
    __shared__ float r2[4][DF];
    const int wl = threadIdx.x >> 6;
    r1[wl][lane] = s1;
    r2[wl][lane] = s2;
    __syncthreads();
    if (threadIdx.x < DF) {
      const int d = threadIdx.x;
      float a = r1[0][d] + r1[1][d] + r1[2][d] + r1[3][d];
      float b = r2[0][d] + r2[1][d] + r2[2][d] + r2[3][d];
      atomicAdd(sums + d, a);
      atomicAdd(sums + DF + d, b);
    }
  }
}

__global__ void denom_kernel(const float* __restrict__ Mv,
                             const int* __restrict__ cluster,
                             const unsigned* __restrict__ mmax_u,
                             float* __restrict__ denom) {
  int i = blockIdx.x * blockDim.x + threadIdx.x;
  if (i < NPTS) {
    int c = cluster[i];
    atomicAdd(denom + c, __expf(Mv[i] - o2f(mmax_u[c])));
  }
}

__global__ void finalize_kernel(const float* __restrict__ sums,
                                const float* __restrict__ gamma,
                                const float* __restrict__ beta,
                                float* __restrict__ scale,
                                float* __restrict__ shift) {
  int d = threadIdx.x;
  float mean = sums[d] * (1.0f / NPTS);
  float var = sums[DF + d] * (1.0f / NPTS) - mean * mean;
  float s = gamma[d] * rsqrtf(var + BN_EPS);
  scale[d] = s;
  shift[d] = fmaf(-mean, s, beta[d]);
}

extern "C" void kernel_launch(void* const* d_in, const int* in_sizes, int n_in,
                              void* d_out, int out_size, void* d_ws,
                              size_t ws_size, hipStream_t stream) {
  const float* x = (const float*)d_in[1];
  const int* cluster = (const int*)d_in[2];
  const float* Wv = (const float*)d_in[3];
  const float* bv = (const float*)d_in[4];
  const float* Wk = (const float*)d_in[5];
  const float* bk = (const float*)d_in[6];
  const float* Wq = (const float*)d_in[7];
  const float* bq = (const float*)d_in[8];
  const float* gamma = (const float*)d_in[9];
  const float* beta = (const float*)d_in[10];
  float* out = (float*)d_out;

  float* ws = (float*)d_ws;
  unsigned* q_u = (unsigned*)ws;
  unsigned* mmax_u = (unsigned*)(ws + 640000);
  float* denom = ws + 650000;
  float* sums = ws + 660000;
  float* scale = ws + 660128;
  float* shift = ws + 660192;
  float* Mv = ws + 660256;

  // zero q_u / mmax_u / denom / sums (0u == sortable "-inf" sentinel)
  hipMemsetAsync(d_ws, 0, 660256 * sizeof(float), stream);

  proj_kernel<0><<<NBLK, 256, 0, stream>>>(x, cluster, Wq, bq, q_u, mmax_u,
                                           denom, Mv, sums, scale, shift, out);
  proj_kernel<1><<<NBLK, 256, 0, stream>>>(x, cluster, Wk, bk, q_u, mmax_u,
                                           denom, Mv, sums, scale, shift, out);
  denom_kernel<<<(NPTS + 255) / 256, 256, 0, stream>>>(Mv, cluster, mmax_u,
                                                       denom);
  proj_kernel<2><<<NBLK, 256, 0, stream>>>(x, cluster, Wv, bv, q_u, mmax_u,
                                           denom, Mv, sums, scale, shift, out);
  finalize_kernel<<<1, 64, 0, stream>>>(sums, gamma, beta, scale, shift);
  proj_kernel<3><<<NBLK, 256, 0, stream>>>(x, cluster, Wv, bv, q_u, mmax_u,
                                           denom, Mv, sums, scale, shift, out);
}

// Round 2
// 779.444 us; speedup vs baseline: 1.2408x; 1.2408x over previous
//
#include <hip/hip_runtime.h>
#include <cstddef>

#define NPTS 500000
#define DF 64
#define NC 10000
#define BN_EPS 1e-5f

#define TPB 256
#define PTILE 64
#define NTILES ((NPTS + PTILE - 1) / PTILE)  // 7813
#define NBLK 1024
#define LSTR 68  // LDS row stride (floats): 64 + 4 pad, keeps 16B alignment

// ---- order-preserving float<->uint encoding (for atomic max on floats) ----
__device__ __forceinline__ unsigned f2o(float f) {
  unsigned u = __float_as_uint(f);
  return (u & 0x80000000u) ? ~u : (u | 0x80000000u);
}
__device__ __forceinline__ float o2f(unsigned u) {
  return __uint_as_float((u & 0x80000000u) ? (u ^ 0x80000000u) : ~u);
}

// ws layout (float/uint units):
// 0        : q_u     [NC*DF]   sortable-uint segment max of Q projections
// 640000   : mmax_u  [NC]      sortable-uint segment max of M
// 650000   : denom   [NC]      segment sum of exp
// 660000   : sums    [2*DF]    [sum h | sum h^2]
// 660128   : scale   [DF]
// 660192   : shift   [DF]
// 660256   : Mv      [NPTS]

// MODE 0: Q proj -> atomicMax q_u
// MODE 1: K proj -> M = dot(q[c],k), store Mv, atomicMax mmax_u
// MODE 2: V proj -> h = attn*v, accumulate BN stats (no h store)
// MODE 3: V proj -> h, normalize + relu, write out
//
// Structure: W^T staged in LDS once per block; per tile, 64 points of x
// staged coalesced into LDS; each thread computes a 4-point x 4-feature
// register block (fg = tid&15 -> features fg*4..+3, pg = tid>>4 -> points
// pg*4..+3). 8 ds_read_b128 per 64 FMAs -> VALU-bound inner loop.
template <int MODE>
__launch_bounds__(TPB, 4)
__global__ void proj_kernel(
    const float* __restrict__ x, const int* __restrict__ cluster,
    const float* __restrict__ W, const float* __restrict__ bias,
    unsigned* __restrict__ q_u, unsigned* __restrict__ mmax_u,
    const float* __restrict__ denom, float* __restrict__ Mv,
    float* __restrict__ sums, const float* __restrict__ scale,
    const float* __restrict__ shift, float* __restrict__ out) {
  __shared__ float Wt[DF * LSTR];     // Wt[j][f] = W[f][j]
  __shared__ float xs[PTILE * LSTR];  // xs[p][j]
  __shared__ int cs[PTILE];

  const int tid = threadIdx.x;
  const int fg = tid & 15;  // feature group
  const int pg = tid >> 4;  // point group
  const int f0 = fg * 4;

  // ---- stage W transposed (once per block) ----
  {
    const int f = tid & 63;
    const int jb = (tid >> 6) * 16;
#pragma unroll
    for (int i = 0; i < 4; ++i) {
      float4 wr = *(const float4*)(W + f * DF + jb + i * 4);
      Wt[(jb + i * 4 + 0) * LSTR + f] = wr.x;
      Wt[(jb + i * 4 + 1) * LSTR + f] = wr.y;
      Wt[(jb + i * 4 + 2) * LSTR + f] = wr.z;
      Wt[(jb + i * 4 + 3) * LSTR + f] = wr.w;
    }
  }
  const float4 bv4 = *(const float4*)(bias + f0);
  float4 sc4 = make_float4(0.f, 0.f, 0.f, 0.f);
  float4 sh4 = make_float4(0.f, 0.f, 0.f, 0.f);
  if (MODE == 3) {
    sc4 = *(const float4*)(scale + f0);
    sh4 = *(const float4*)(shift + f0);
  }
  float4 s1 = make_float4(0.f, 0.f, 0.f, 0.f);
  float4 s2 = make_float4(0.f, 0.f, 0.f, 0.f);

  for (int t = blockIdx.x; t < NTILES; t += gridDim.x) {
    const int pbase = t * PTILE;
    __syncthreads();  // protect xs/Wt from previous readers
    // ---- stage x tile, fully coalesced ----
#pragma unroll
    for (int i = 0; i < 4; ++i) {
      int idx = tid + i * TPB;  // one float4 each, 0..1023
      int p = idx >> 4;
      int j = (idx & 15) * 4;
      int gp = pbase + p;
      float4 v = make_float4(0.f, 0.f, 0.f, 0.f);
      if (gp < NPTS) v = *(const float4*)(x + (size_t)gp * DF + j);
      *(float4*)(xs + p * LSTR + j) = v;
    }
    if (tid < PTILE) {
      int gp = pbase + tid;
      cs[tid] = (gp < NPTS) ? cluster[gp] : 0;
    }
    __syncthreads();

    // ---- register-blocked GEMM: acc[pp] = x[p] . W[f0..f0+3] + b ----
    float4 acc[4];
#pragma unroll
    for (int pp = 0; pp < 4; ++pp) acc[pp] = bv4;
#pragma unroll 4
    for (int j4 = 0; j4 < 16; ++j4) {
      float4 wv[4];  // wv[e][comp] = W[f0+comp][j4*4+e]
#pragma unroll
      for (int e = 0; e < 4; ++e)
        wv[e] = *(const float4*)(Wt + (j4 * 4 + e) * LSTR + f0);
#pragma unroll
      for (int pp = 0; pp < 4; ++pp) {
        float4 xv = *(const float4*)(xs + (pg * 4 + pp) * LSTR + j4 * 4);
        acc[pp].x = fmaf(xv.x, wv[0].x, acc[pp].x);
        acc[pp].y = fmaf(xv.x, wv[0].y, acc[pp].y);
        acc[pp].z = fmaf(xv.x, wv[0].z, acc[pp].z);
        acc[pp].w = fmaf(xv.x, wv[0].w, acc[pp].w);
        acc[pp].x = fmaf(xv.y, wv[1].x, acc[pp].x);
        acc[pp].y = fmaf(xv.y, wv[1].y, acc[pp].y);
        acc[pp].z = fmaf(xv.y, wv[1].z, acc[pp].z);
        acc[pp].w = fmaf(xv.y, wv[1].w, acc[pp].w);
        acc[pp].x = fmaf(xv.z, wv[2].x, acc[pp].x);
        acc[pp].y = fmaf(xv.z, wv[2].y, acc[pp].y);
        acc[pp].z = fmaf(xv.z, wv[2].z, acc[pp].z);
        acc[pp].w = fmaf(xv.z, wv[2].w, acc[pp].w);
        acc[pp].x = fmaf(xv.w, wv[3].x, acc[pp].x);
        acc[pp].y = fmaf(xv.w, wv[3].y, acc[pp].y);
        acc[pp].z = fmaf(xv.w, wv[3].z, acc[pp].z);
        acc[pp].w = fmaf(xv.w, wv[3].w, acc[pp].w);
      }
    }

    // ---- mode-specific epilogue ----
#pragma unroll
    for (int pp = 0; pp < 4; ++pp) {
      const int lp = pg * 4 + pp;
      const int p = pbase + lp;
      if (MODE == 0) {
        if (p < NPTS) {
          unsigned* dst = q_u + (size_t)cs[lp] * DF + f0;
          atomicMax(dst + 0, f2o(acc[pp].x));
          atomicMax(dst + 1, f2o(acc[pp].y));
          atomicMax(dst + 2, f2o(acc[pp].z));
          atomicMax(dst + 3, f2o(acc[pp].w));
        }
      } else if (MODE == 1) {
        float partial = 0.f;
        if (p < NPTS) {
          const uint4 qu = *(const uint4*)(q_u + (size_t)cs[lp] * DF + f0);
          partial = o2f(qu.x) * acc[pp].x + o2f(qu.y) * acc[pp].y +
                    o2f(qu.z) * acc[pp].z + o2f(qu.w) * acc[pp].w;
        }
        // reduce across the 16 lanes sharing this point (fg bits = lane&15)
        partial += __shfl_xor(partial, 1, 64);
        partial += __shfl_xor(partial, 2, 64);
        partial += __shfl_xor(partial, 4, 64);
        partial += __shfl_xor(partial, 8, 64);
        if (fg == 0 && p < NPTS) {
          Mv[p] = partial;
          atomicMax(mmax_u + cs[lp], f2o(partial));
        }
      } else {
        if (p < NPTS) {
          const int c = cs[lp];
          const float attn = __expf(Mv[p] - o2f(mmax_u[c])) / denom[c];
          float4 h;
          h.x = attn * acc[pp].x;
          h.y = attn * acc[pp].y;
          h.z = attn * acc[pp].z;
          h.w = attn * acc[pp].w;
          if (MODE == 2) {
            s1.x += h.x; s1.y += h.y; s1.z += h.z; s1.w += h.w;
            s2.x += h.x * h.x; s2.y += h.y * h.y;
            s2.z += h.z * h.z; s2.w += h.w * h.w;
          } else {
            float4 r;
            r.x = fmaxf(fmaf(h.x, sc4.x, sh4.x), 0.f);
            r.y = fmaxf(fmaf(h.y, sc4.y, sh4.y), 0.f);
            r.z = fmaxf(fmaf(h.z, sc4.z, sh4.z), 0.f);
            r.w = fmaxf(fmaf(h.w, sc4.w, sh4.w), 0.f);
            *(float4*)(out + (size_t)p * DF + f0) = r;
          }
        }
      }
    }
  }

  if constexpr (MODE == 2) {
    // block-reduce BN partial sums; alias xs as scratch (done with tiles)
    __syncthreads();
    float* red = xs;  // red1 = xs[0..1023], red2 = xs[1024..2047]
    *(float4*)(red + pg * DF + f0) = s1;
    *(float4*)(red + 1024 + pg * DF + f0) = s2;
    __syncthreads();
    if (tid < DF) {
      float a = 0.f, b = 0.f;
#pragma unroll
      for (int g = 0; g < 16; ++g) {
        a += red[g * DF + tid];
        b += red[1024 + g * DF + tid];
      }
      atomicAdd(sums + tid, a);
      atomicAdd(sums + DF + tid, b);
    }
  }
}

__global__ void denom_kernel(const float* __restrict__ Mv,
                             const int* __restrict__ cluster,
                             const unsigned* __restrict__ mmax_u,
                             float* __restrict__ denom) {
  int i = blockIdx.x * blockDim.x + threadIdx.x;
  if (i < NPTS) {
    int c = cluster[i];
    atomicAdd(denom + c, __expf(Mv[i] - o2f(mmax_u[c])));
  }
}

__global__ void finalize_kernel(const float* __restrict__ sums,
                                const float* __restrict__ gamma,
                                const float* __restrict__ beta,
                                float* __restrict__ scale,
                                float* __restrict__ shift) {
  int d = threadIdx.x;
  float mean = sums[d] * (1.0f / NPTS);
  float var = sums[DF + d] * (1.0f / NPTS) - mean * mean;
  float s = gamma[d] * rsqrtf(var + BN_EPS);
  scale[d] = s;
  shift[d] = fmaf(-mean, s, beta[d]);
}

extern "C" void kernel_launch(void* const* d_in, const int* in_sizes, int n_in,
                              void* d_out, int out_size, void* d_ws,
                              size_t ws_size, hipStream_t stream) {
  const float* x = (const float*)d_in[1];
  const int* cluster = (const int*)d_in[2];
  const float* Wv = (const float*)d_in[3];
  const float* bv = (const float*)d_in[4];
  const float* Wk = (const float*)d_in[5];
  const float* bk = (const float*)d_in[6];
  const float* Wq = (const float*)d_in[7];
  const float* bq = (const float*)d_in[8];
  const float* gamma = (const float*)d_in[9];
  const float* beta = (const float*)d_in[10];
  float* out = (float*)d_out;

  float* ws = (float*)d_ws;
  unsigned* q_u = (unsigned*)ws;
  unsigned* mmax_u = (unsigned*)(ws + 640000);
  float* denom = ws + 650000;
  float* sums = ws + 660000;
  float* scale = ws + 660128;
  float* shift = ws + 660192;
  float* Mv = ws + 660256;

  // zero q_u / mmax_u / denom / sums (0u == sortable "-inf" sentinel)
  hipMemsetAsync(d_ws, 0, 660256 * sizeof(float), stream);

  proj_kernel<0><<<NBLK, TPB, 0, stream>>>(x, cluster, Wq, bq, q_u, mmax_u,
                                           denom, Mv, sums, scale, shift, out);
  proj_kernel<1><<<NBLK, TPB, 0, stream>>>(x, cluster, Wk, bk, q_u, mmax_u,
                                           denom, Mv, sums, scale, shift, out);
  denom_kernel<<<(NPTS + 255) / 256, 256, 0, stream>>>(Mv, cluster, mmax_u,
                                                       denom);
  proj_kernel<2><<<NBLK, TPB, 0, stream>>>(x, cluster, Wv, bv, q_u, mmax_u,
                                           denom, Mv, sums, scale, shift, out);
  finalize_kernel<<<1, 64, 0, stream>>>(sums, gamma, beta, scale, shift);
  proj_kernel<3><<<NBLK, TPB, 0, stream>>>(x, cluster, Wv, bv, q_u, mmax_u,
                                           denom, Mv, sums, scale, shift, out);
}

// Round 3
// 591.706 us; speedup vs baseline: 1.6345x; 1.3173x over previous
//
#include <hip/hip_runtime.h>
#include <cstddef>

#define NPTS 500000
#define DF 64
#define NC 10000
#define BN_EPS 1e-5f

#define TPB 256
#define PTILE 64
#define NTILES ((NPTS + PTILE - 1) / PTILE)  // 7813
#define NBLK 1024
#define LSTR 68  // LDS row stride (floats): 64 + 4 pad, keeps 16B alignment

// ---- order-preserving float<->uint encoding (for atomic max on floats) ----
__device__ __forceinline__ unsigned f2o(float f) {
  unsigned u = __float_as_uint(f);
  return (u & 0x80000000u) ? ~u : (u | 0x80000000u);
}
__device__ __forceinline__ float o2f(unsigned u) {
  return __uint_as_float((u & 0x80000000u) ? (u ^ 0x80000000u) : ~u);
}

// ws layout (float/uint units):
// 0        : q_u     [NC*DF]   sortable-uint segment max of Q projections
// 640000   : mmax_u  [NC]      sortable-uint segment max of M
// 650000   : denom   [NC]      segment sum of exp
// 660000   : sums    [2*DF]    [sum h | sum h^2]
// 660128   : scale   [DF]
// 660192   : shift   [DF]
// 660256   : Mv      [NPTS]

// MODE 0: Q proj -> segment max into q_u (read-filtered atomics)
// MODE 1: K proj -> M = dot(q[c],k), store Mv, atomicMax mmax_u
// MODE 2: V proj -> h = attn*v, accumulate BN stats (no h store)
// MODE 3: V proj -> h, normalize + relu, write out
template <int MODE>
__launch_bounds__(TPB, 4)
__global__ void proj_kernel(
    const float* __restrict__ x, const int* __restrict__ cluster,
    const float* __restrict__ W, const float* __restrict__ bias,
    unsigned* __restrict__ q_u, unsigned* __restrict__ mmax_u,
    const float* __restrict__ denom, float* __restrict__ Mv,
    float* __restrict__ sums, const float* __restrict__ scale,
    const float* __restrict__ shift, float* __restrict__ out) {
  __shared__ float Wt[DF * LSTR];     // Wt[j][f] = W[f][j]
  __shared__ float xs[PTILE * LSTR];  // xs[p][j]
  __shared__ int cs[PTILE];

  const int tid = threadIdx.x;
  const int fg = tid & 15;  // feature group
  const int pg = tid >> 4;  // point group
  const int f0 = fg * 4;

  // ---- stage W transposed (once per block) ----
  {
    const int f = tid & 63;
    const int jb = (tid >> 6) * 16;
#pragma unroll
    for (int i = 0; i < 4; ++i) {
      float4 wr = *(const float4*)(W + f * DF + jb + i * 4);
      Wt[(jb + i * 4 + 0) * LSTR + f] = wr.x;
      Wt[(jb + i * 4 + 1) * LSTR + f] = wr.y;
      Wt[(jb + i * 4 + 2) * LSTR + f] = wr.z;
      Wt[(jb + i * 4 + 3) * LSTR + f] = wr.w;
    }
  }
  const float4 bv4 = *(const float4*)(bias + f0);
  float4 sc4 = make_float4(0.f, 0.f, 0.f, 0.f);
  float4 sh4 = make_float4(0.f, 0.f, 0.f, 0.f);
  if (MODE == 3) {
    sc4 = *(const float4*)(scale + f0);
    sh4 = *(const float4*)(shift + f0);
  }
  float4 s1 = make_float4(0.f, 0.f, 0.f, 0.f);
  float4 s2 = make_float4(0.f, 0.f, 0.f, 0.f);

  for (int t = blockIdx.x; t < NTILES; t += gridDim.x) {
    const int pbase = t * PTILE;
    __syncthreads();  // protect xs/Wt from previous readers
    // ---- stage x tile, fully coalesced ----
#pragma unroll
    for (int i = 0; i < 4; ++i) {
      int idx = tid + i * TPB;  // one float4 each, 0..1023
      int p = idx >> 4;
      int j = (idx & 15) * 4;
      int gp = pbase + p;
      float4 v = make_float4(0.f, 0.f, 0.f, 0.f);
      if (gp < NPTS) v = *(const float4*)(x + (size_t)gp * DF + j);
      *(float4*)(xs + p * LSTR + j) = v;
    }
    if (tid < PTILE) {
      int gp = pbase + tid;
      cs[tid] = (gp < NPTS) ? cluster[gp] : 0;
    }
    __syncthreads();

    // ---- register-blocked GEMM: acc[pp] = x[p] . W[f0..f0+3] + b ----
    float4 acc[4];
#pragma unroll
    for (int pp = 0; pp < 4; ++pp) acc[pp] = bv4;
#pragma unroll 4
    for (int j4 = 0; j4 < 16; ++j4) {
      float4 wv[4];  // wv[e][comp] = W[f0+comp][j4*4+e]
#pragma unroll
      for (int e = 0; e < 4; ++e)
        wv[e] = *(const float4*)(Wt + (j4 * 4 + e) * LSTR + f0);
#pragma unroll
      for (int pp = 0; pp < 4; ++pp) {
        float4 xv = *(const float4*)(xs + (pg * 4 + pp) * LSTR + j4 * 4);
        acc[pp].x = fmaf(xv.x, wv[0].x, acc[pp].x);
        acc[pp].y = fmaf(xv.x, wv[0].y, acc[pp].y);
        acc[pp].z = fmaf(xv.x, wv[0].z, acc[pp].z);
        acc[pp].w = fmaf(xv.x, wv[0].w, acc[pp].w);
        acc[pp].x = fmaf(xv.y, wv[1].x, acc[pp].x);
        acc[pp].y = fmaf(xv.y, wv[1].y, acc[pp].y);
        acc[pp].z = fmaf(xv.y, wv[1].z, acc[pp].z);
        acc[pp].w = fmaf(xv.y, wv[1].w, acc[pp].w);
        acc[pp].x = fmaf(xv.z, wv[2].x, acc[pp].x);
        acc[pp].y = fmaf(xv.z, wv[2].y, acc[pp].y);
        acc[pp].z = fmaf(xv.z, wv[2].z, acc[pp].z);
        acc[pp].w = fmaf(xv.z, wv[2].w, acc[pp].w);
        acc[pp].x = fmaf(xv.w, wv[3].x, acc[pp].x);
        acc[pp].y = fmaf(xv.w, wv[3].y, acc[pp].y);
        acc[pp].z = fmaf(xv.w, wv[3].z, acc[pp].z);
        acc[pp].w = fmaf(xv.w, wv[3].w, acc[pp].w);
      }
    }

    // ---- mode-specific epilogue ----
#pragma unroll
    for (int pp = 0; pp < 4; ++pp) {
      const int lp = pg * 4 + pp;
      const int p = pbase + lp;
      if (MODE == 0) {
        if (p < NPTS) {
          unsigned* dst = q_u + (size_t)cs[lp] * DF + f0;
          // q_u is monotonically non-decreasing, so a (possibly stale)
          // plain read can only under-report: skipping when new <= cached
          // is race-safe and kills ~90% of the atomics.
          const uint4 cur = *(const uint4*)dst;
          const unsigned ex = f2o(acc[pp].x);
          const unsigned ey = f2o(acc[pp].y);
          const unsigned ez = f2o(acc[pp].z);
          const unsigned ew = f2o(acc[pp].w);
          if (ex > cur.x) atomicMax(dst + 0, ex);
          if (ey > cur.y) atomicMax(dst + 1, ey);
          if (ez > cur.z) atomicMax(dst + 2, ez);
          if (ew > cur.w) atomicMax(dst + 3, ew);
        }
      } else if (MODE == 1) {
        float partial = 0.f;
        if (p < NPTS) {
          const uint4 qu = *(const uint4*)(q_u + (size_t)cs[lp] * DF + f0);
          partial = o2f(qu.x) * acc[pp].x + o2f(qu.y) * acc[pp].y +
                    o2f(qu.z) * acc[pp].z + o2f(qu.w) * acc[pp].w;
        }
        // reduce across the 16 lanes sharing this point (fg bits = lane&15)
        partial += __shfl_xor(partial, 1, 64);
        partial += __shfl_xor(partial, 2, 64);
        partial += __shfl_xor(partial, 4, 64);
        partial += __shfl_xor(partial, 8, 64);
        if (fg == 0 && p < NPTS) {
          Mv[p] = partial;
          const unsigned e = f2o(partial);
          unsigned* mm = mmax_u + cs[lp];
          if (e > *mm) atomicMax(mm, e);
        }
      } else {
        if (p < NPTS) {
          const int c = cs[lp];
          const float attn = __expf(Mv[p] - o2f(mmax_u[c])) / denom[c];
          float4 h;
          h.x = attn * acc[pp].x;
          h.y = attn * acc[pp].y;
          h.z = attn * acc[pp].z;
          h.w = attn * acc[pp].w;
          if (MODE == 2) {
            s1.x += h.x; s1.y += h.y; s1.z += h.z; s1.w += h.w;
            s2.x += h.x * h.x; s2.y += h.y * h.y;
            s2.z += h.z * h.z; s2.w += h.w * h.w;
          } else {
            float4 r;
            r.x = fmaxf(fmaf(h.x, sc4.x, sh4.x), 0.f);
            r.y = fmaxf(fmaf(h.y, sc4.y, sh4.y), 0.f);
            r.z = fmaxf(fmaf(h.z, sc4.z, sh4.z), 0.f);
            r.w = fmaxf(fmaf(h.w, sc4.w, sh4.w), 0.f);
            *(float4*)(out + (size_t)p * DF + f0) = r;
          }
        }
      }
    }
  }

  if constexpr (MODE == 2) {
    // block-reduce BN partial sums; alias xs as scratch (done with tiles)
    __syncthreads();
    float* red = xs;  // red1 = xs[0..1023], red2 = xs[1024..2047]
    *(float4*)(red + pg * DF + f0) = s1;
    *(float4*)(red + 1024 + pg * DF + f0) = s2;
    __syncthreads();
    if (tid < DF) {
      float a = 0.f, b = 0.f;
#pragma unroll
      for (int g = 0; g < 16; ++g) {
        a += red[g * DF + tid];
        b += red[1024 + g * DF + tid];
      }
      atomicAdd(sums + tid, a);
      atomicAdd(sums + DF + tid, b);
    }
  }
}

__global__ void denom_kernel(const float* __restrict__ Mv,
                             const int* __restrict__ cluster,
                             const unsigned* __restrict__ mmax_u,
                             float* __restrict__ denom) {
  int i = blockIdx.x * blockDim.x + threadIdx.x;
  if (i < NPTS) {
    int c = cluster[i];
    atomicAdd(denom + c, __expf(Mv[i] - o2f(mmax_u[c])));
  }
}

__global__ void finalize_kernel(const float* __restrict__ sums,
                                const float* __restrict__ gamma,
                                const float* __restrict__ beta,
                                float* __restrict__ scale,
                                float* __restrict__ shift) {
  int d = threadIdx.x;
  float mean = sums[d] * (1.0f / NPTS);
  float var = sums[DF + d] * (1.0f / NPTS) - mean * mean;
  float s = gamma[d] * rsqrtf(var + BN_EPS);
  scale[d] = s;
  shift[d] = fmaf(-mean, s, beta[d]);
}

extern "C" void kernel_launch(void* const* d_in, const int* in_sizes, int n_in,
                              void* d_out, int out_size, void* d_ws,
                              size_t ws_size, hipStream_t stream) {
  const float* x = (const float*)d_in[1];
  const int* cluster = (const int*)d_in[2];
  const float* Wv = (const float*)d_in[3];
  const float* bv = (const float*)d_in[4];
  const float* Wk = (const float*)d_in[5];
  const float* bk = (const float*)d_in[6];
  const float* Wq = (const float*)d_in[7];
  const float* bq = (const float*)d_in[8];
  const float* gamma = (const float*)d_in[9];
  const float* beta = (const float*)d_in[10];
  float* out = (float*)d_out;

  float* ws = (float*)d_ws;
  unsigned* q_u = (unsigned*)ws;
  unsigned* mmax_u = (unsigned*)(ws + 640000);
  float* denom = ws + 650000;
  float* sums = ws + 660000;
  float* scale = ws + 660128;
  float* shift = ws + 660192;
  float* Mv = ws + 660256;

  // zero q_u / mmax_u / denom / sums (0u == sortable "-inf" sentinel)
  hipMemsetAsync(d_ws, 0, 660256 * sizeof(float), stream);

  proj_kernel<0><<<NBLK, TPB, 0, stream>>>(x, cluster, Wq, bq, q_u, mmax_u,
                                           denom, Mv, sums, scale, shift, out);
  proj_kernel<1><<<NBLK, TPB, 0, stream>>>(x, cluster, Wk, bk, q_u, mmax_u,
                                           denom, Mv, sums, scale, shift, out);
  denom_kernel<<<(NPTS + 255) / 256, 256, 0, stream>>>(Mv, cluster, mmax_u,
                                                       denom);
  proj_kernel<2><<<NBLK, TPB, 0, stream>>>(x, cluster, Wv, bv, q_u, mmax_u,
                                           denom, Mv, sums, scale, shift, out);
  finalize_kernel<<<1, 64, 0, stream>>>(sums, gamma, beta, scale, shift);
  proj_kernel<3><<<NBLK, TPB, 0, stream>>>(x, cluster, Wv, bv, q_u, mmax_u,
                                           denom, Mv, sums, scale, shift, out);
}